// Round 7
// baseline (379.264 us; speedup 1.0000x reference)
//
#include <hip/hip_runtime.h>

typedef __attribute__((ext_vector_type(8))) short short8;
typedef __attribute__((ext_vector_type(4))) float f32x4;

__device__ __forceinline__ float bf2f(short s) {
  return __uint_as_float(((unsigned)(unsigned short)s) << 16);
}
__device__ __forceinline__ unsigned short f2bf(float f) {
  unsigned u = __float_as_uint(f);
  unsigned rounding = 0x7fffu + ((u >> 16) & 1u);
  return (unsigned short)((u + rounding) >> 16);
}

// ---------------- prep: fp32 -> bf16 conversions + combined weight/bias ----
__global__ void prep_kernel(const float* __restrict__ feats, const float* __restrict__ Wd,
                            const float* __restrict__ Wl, const float* __restrict__ Wr,
                            const float* __restrict__ Gl, const float* __restrict__ Gr,
                            const float* __restrict__ bl, const float* __restrict__ br,
                            const float* __restrict__ bgl, const float* __restrict__ bgr,
                            unsigned short* __restrict__ featsB, unsigned short* __restrict__ WdB,
                            unsigned short* __restrict__ WcB, float* __restrict__ bc)
{
  int idx = blockIdx.x * 256 + threadIdx.x;
  if (idx < 393216) {
    featsB[idx] = f2bf(feats[idx]);
  } else if (idx < 524288) {
    int j = idx - 393216;
    WdB[j] = f2bf(Wd[j]);
  } else if (idx < 1048576) {
    int j = idx - 524288;          // Wc[1024][512]: o = j>>9, k = j&511
    int o = j >> 9, k = j & 511;
    float v;
    if (k < 256) v = (o < 256) ? Wl[o*256 + k] : Gl[(o-256)*256 + k];
    else { int k2 = k - 256; v = (o < 256) ? Wr[o*256 + k2] : Gr[(o-256)*256 + k2]; }
    WcB[j] = f2bf(v);
  } else if (idx < 1049600) {
    int o = idx - 1048576;
    bc[o] = (o < 256) ? bl[o] + br[o] : bgl[o-256] + bgr[o-256];
  }
}

// ---------------- h = feats @ Wd.T + bd  (768x512 @ 512x256) ---------------
__global__ __launch_bounds__(256) void hgemm_kernel(const unsigned short* __restrict__ A,
                                                    const unsigned short* __restrict__ W,
                                                    const float* __restrict__ bd,
                                                    unsigned short* __restrict__ C)
{
  __shared__ __align__(16) unsigned short As[64][72];
  __shared__ __align__(16) unsigned short Ws[64][72];
  int p0 = blockIdx.x * 64;
  int n0 = blockIdx.y * 64;
  int tid = threadIdx.x;
  int wave = tid >> 6, lane = tid & 63;
  f32x4 acc[4];
  #pragma unroll
  for (int i = 0; i < 4; ++i)
    #pragma unroll
    for (int j = 0; j < 4; ++j) acc[i][j] = 0.f;

  int lr = tid >> 3;
  int c8 = (tid & 7) * 8;
  for (int kt = 0; kt < 8; ++kt) {
    int kb = kt * 64;
    #pragma unroll
    for (int rr = 0; rr < 64; rr += 32) {
      int row = lr + rr;
      *(short8*)(&As[row][c8]) = *(const short8*)(A + (size_t)(p0 + row)*512 + kb + c8);
      *(short8*)(&Ws[row][c8]) = *(const short8*)(W + (size_t)(n0 + row)*512 + kb + c8);
    }
    __syncthreads();
    int q8 = (lane >> 4) * 8;
    #pragma unroll
    for (int kk = 0; kk < 2; ++kk) {
      short8 b = *(const short8*)(&Ws[wave*16 + (lane & 15)][kk*32 + q8]);
      #pragma unroll
      for (int mt = 0; mt < 4; ++mt) {
        short8 a = *(const short8*)(&As[mt*16 + (lane & 15)][kk*32 + q8]);
        acc[mt] = __builtin_amdgcn_mfma_f32_16x16x32_bf16(a, b, acc[mt], 0, 0, 0);
      }
    }
    __syncthreads();
  }
  int o = n0 + wave*16 + (lane & 15);
  float bias = bd[o];
  #pragma unroll
  for (int mt = 0; mt < 4; ++mt)
    #pragma unroll
    for (int r = 0; r < 4; ++r) {
      int row = p0 + mt*16 + (lane >> 4)*4 + r;
      C[row*256 + o] = f2bf(acc[mt][r] + bias);
    }
}

// ---------------- one span iteration: GEMM + fused gate epilogue -----------
__global__ __launch_bounds__(256) void iter_kernel(const unsigned short* __restrict__ htp,
                                                   const unsigned short* __restrict__ Wc,
                                                   const float* __restrict__ bc,
                                                   unsigned short* __restrict__ htn,
                                                   int Mvalid)
{
  __shared__ __align__(16) unsigned short As[64][72];
  __shared__ __align__(16) unsigned short Ws[64][72];
  __shared__ float Cs[64][64];
  int p0 = blockIdx.x * 64;
  int n0 = blockIdx.y * 16;
  int tid = threadIdx.x;
  int wave = tid >> 6, lane = tid & 63;
  f32x4 acc[4];
  #pragma unroll
  for (int i = 0; i < 4; ++i)
    #pragma unroll
    for (int j = 0; j < 4; ++j) acc[i][j] = 0.f;

  int lr = tid >> 3;
  int c8 = (tid & 7) * 8;
  for (int kt = 0; kt < 8; ++kt) {
    int kb = kt * 64;
    int shift = kb >> 8;
    int kcol = kb & 255;
    #pragma unroll
    for (int rr = 0; rr < 64; rr += 32) {
      int row = lr + rr;
      int grow = p0 + row + shift; if (grow > 767) grow = 767;
      *(short8*)(&As[row][c8]) = *(const short8*)(htp + (size_t)grow*256 + kcol + c8);
      int o = (row >> 4)*256 + n0 + (row & 15);
      *(short8*)(&Ws[row][c8]) = *(const short8*)(Wc + (size_t)o*512 + kb + c8);
    }
    __syncthreads();
    int q8 = (lane >> 4) * 8;
    #pragma unroll
    for (int kk = 0; kk < 2; ++kk) {
      short8 b = *(const short8*)(&Ws[wave*16 + (lane & 15)][kk*32 + q8]);
      #pragma unroll
      for (int mt = 0; mt < 4; ++mt) {
        short8 a = *(const short8*)(&As[mt*16 + (lane & 15)][kk*32 + q8]);
        acc[mt] = __builtin_amdgcn_mfma_f32_16x16x32_bf16(a, b, acc[mt], 0, 0, 0);
      }
    }
    __syncthreads();
  }
  #pragma unroll
  for (int mt = 0; mt < 4; ++mt)
    #pragma unroll
    for (int r = 0; r < 4; ++r)
      Cs[mt*16 + (lane >> 4)*4 + r][wave*16 + (lane & 15)] = acc[mt][r];
  __syncthreads();

  int dl = tid & 15;
  int d = n0 + dl;
  float bz = bc[d], b0 = bc[256 + d], b1 = bc[512 + d], b2v = bc[768 + d];
  for (int pr = tid >> 4; pr < 64; pr += 16) {
    int p = p0 + pr;
    if (p >= Mvalid) continue;
    float z  = Cs[pr][dl]      + bz;
    float g0 = Cs[pr][16 + dl] + b0;
    float g1 = Cs[pr][32 + dl] + b1;
    float g2 = Cs[pr][48 + dl] + b2v;
    float l = bf2f((short)htp[p*256 + d]);
    float r = bf2f((short)htp[(p+1)*256 + d]);
    float hh = 4.f / (1.f + __expf(-z)) - 2.f;
    float mg = fmaxf(g0, fmaxf(g1, g2));
    float e0 = __expf(g0 - mg), e1 = __expf(g1 - mg), e2 = __expf(g2 - mg);
    float inv = 1.f / (e0 + e1 + e2);
    htn[p*256 + d] = f2bf((e0*hh + e1*l + e2*r) * inv);
  }
}

// ---------------- band: log scores, row max, normalized exp ----------------
__global__ __launch_bounds__(128) void band_kernel(const unsigned short* __restrict__ htall,
                                                   const float* __restrict__ Wt,
                                                   const float* __restrict__ bt,
                                                   float* __restrict__ Bband,   // [769][96] log
                                                   float* __restrict__ Xn,      // [769][96] exp(B-mu)
                                                   float* __restrict__ mu)      // [769]
{
  __shared__ __align__(16) unsigned short rows[8][264];
  __shared__ float sred[96];
  __shared__ float smu;
  int i = blockIdx.x + 1;     // 1..768
  int tid = threadIdx.x;
  for (int q = tid; q < 256; q += 128) {
    int k = q >> 5, cc = (q & 31) * 8;
    int p = i - 8 + k, sl = 7 - k;
    short8 v;
    if (p >= 0) {
      v = *(const short8*)(htall + ((size_t)sl*768 + p)*256 + cc);
    } else {
      for (int j = 0; j < 8; ++j) v[j] = 0;
    }
    *(short8*)(&rows[k][cc]) = v;
  }
  __syncthreads();
  float res = -1e30f;
  if (tid < 96) {
    int t = tid >> 3, k = tid & 7;
    int p = i - 8 + k;
    if (p >= 0) {
      float acc = 0.f;
      for (int dch = 0; dch < 256; dch += 8) {
        float4 wa = *(const float4*)(Wt + t*256 + dch);
        float4 wb = *(const float4*)(Wt + t*256 + dch + 4);
        short8 hv = *(const short8*)(&rows[k][dch]);
        acc += wa.x*bf2f(hv[0]) + wa.y*bf2f(hv[1]) + wa.z*bf2f(hv[2]) + wa.w*bf2f(hv[3])
             + wb.x*bf2f(hv[4]) + wb.y*bf2f(hv[5]) + wb.z*bf2f(hv[6]) + wb.w*bf2f(hv[7]);
      }
      res = acc + bt[t];
    }
    Bband[(size_t)i*96 + tid] = res;
    sred[tid] = res;
  }
  __syncthreads();
  if (tid < 32) {
    float m = fmaxf(sred[tid], fmaxf(sred[tid+32], sred[tid+64]));
    #pragma unroll
    for (int off = 16; off; off >>= 1) m = fmaxf(m, __shfl_down(m, off));
    if (tid == 0) { mu[i] = m; smu = m; }
  }
  __syncthreads();
  if (tid < 96) Xn[(size_t)i*96 + tid] = __expf(res - smu);  // masked -> 0
}

// ---------------- chunk transfer matrices (parallel scan, phase 1) ---------
__global__ __launch_bounds__(256) void chunkT_kernel(const float* __restrict__ Xn,
                                                     const float* __restrict__ mu,
                                                     const float* __restrict__ trans,
                                                     float* __restrict__ T)
{
  int chunk = blockIdx.y;
  int a = chunk * 16;               // steps a+1 .. a+16
  int tid = threadIdx.x;
  int wv = tid >> 6;
  int lane = tid & 63;
  int g = lane / 12;                // 12-lane group within wave (g=5: shadow)
  int t = lane - g * 12;            // tag owned by this lane
  int cidx = blockIdx.x * 20 + wv * 5 + g;
  bool active = (g < 5) && (cidx < 96);
  int c = active ? cidx : 95;
  int s = c / 12, tau = c - s * 12; // basis: na_{a-7+s} = e_tau
  float Etc[12];
  #pragma unroll
  for (int j = 0; j < 12; ++j) Etc[j] = __expf(trans[j*12 + t]);  // E[j][t]
  float NA[8], V[8];
  #pragma unroll
  for (int j = 0; j < 8; ++j) { NA[j] = 0.f; V[j] = 0.f; }
  #pragma unroll
  for (int j = 0; j < 8; ++j) if (j == s) {
    NA[j] = (t == tau) ? 1.f : 0.f;
    V[j]  = Etc[tau];               // v = E^T e_tau -> E[tau][t]
  }
  int gb = (g * 12) * 4;            // bpermute byte base of this group
  #pragma unroll
  for (int m = 1; m <= 16; ++m) {
    const float* xr = Xn + (size_t)(a + m) * 96 + t * 8;
    float4 x0 = *(const float4*)xr;
    float4 x1 = *(const float4*)(xr + 4);
    float sf = __expf(-mu[a + m]);  // uniform state scale for this step
    float na = x0.x*V[0] + x0.y*V[1] + x0.z*V[2] + x0.w*V[3]
             + x1.x*V[4] + x1.y*V[5] + x1.z*V[6] + x1.w*V[7];
    int nai = __float_as_int(na);
    float nb[12];
    #pragma unroll
    for (int j = 0; j < 12; ++j)
      nb[j] = __int_as_float(__builtin_amdgcn_ds_bpermute(gb + j*4, nai));
    float p0 = nb[0]*Etc[0] + nb[1]*Etc[1] + nb[2]*Etc[2]  + nb[3]*Etc[3];
    float p1 = nb[4]*Etc[4] + nb[5]*Etc[5] + nb[6]*Etc[6]  + nb[7]*Etc[7];
    float p2 = nb[8]*Etc[8] + nb[9]*Etc[9] + nb[10]*Etc[10] + nb[11]*Etc[11];
    float v = (p0 + p1) + p2;
    #pragma unroll
    for (int k = 0; k < 7; ++k) { NA[k] = NA[k+1]*sf; V[k] = V[k+1]*sf; }
    NA[7] = na; V[7] = v;           // na already carries e^{-mu} via Xn
  }
  if (active) {
    float* dst = T + (size_t)chunk * 9216 + c;
    #pragma unroll
    for (int j = 0; j < 8; ++j) dst[(size_t)(j*12 + t) * 96] = NA[j];
  }
}

// ---------------- sequential combine (phase 2) + gold ----------------------
// T chunks staged through double-buffered LDS (NO register-array indirection
// -> no scratch spill, the R5 failure mode).
__global__ __launch_bounds__(128, 1) void combine_kernel(const float* __restrict__ T,
    const float* __restrict__ Bband, const float* __restrict__ mu,
    const float* __restrict__ trans, const float* __restrict__ bt,
    const int* __restrict__ tags, float* __restrict__ out)
{
  __shared__ float Tl[2][96 * 97];  // 2 x 36.4 KB, +1 row pad (bank spread)
  __shared__ float zs[2][96];
  __shared__ float red[128];
  __shared__ float sc[4];           // [0]=gold, [1]=norm, [2]=musum
  int tid = threadIdx.x;
  int lane = tid & 63;

  if (tid < 64) {                   // gold on wave 0
    float gold = 0.f;
    for (int s = lane; s < 96; s += 64) {
      int a = tags[s*4+0], b = tags[s*4+1], cc = tags[s*4+2], d = tags[s*4+3];
      float v = trans[cc*12 + d];
      int sl = b - a;
      if (sl >= 0 && sl < 8) v += Bband[(size_t)(b+1)*96 + d*8 + (7 - sl)];
      else v += bt[d];
      gold += v;
    }
    #pragma unroll
    for (int off = 32; off; off >>= 1) gold += __shfl_down(gold, off);
    if (lane == 0) sc[0] = gold;
  }
  float mp = 0.f;                   // musum over mu[1..768]
  for (int q = tid; q < 768; q += 128) mp += mu[1 + q];
  red[tid] = mp;
  if (tid < 96) zs[0][tid] = (tid == 94) ? 1.f : 0.f;  // na_0 = onehot(START=10)
  __syncthreads();
  if (tid < 64) {
    float v = red[tid] + red[tid + 64];
    #pragma unroll
    for (int off = 32; off; off >>= 1) v += __shfl_down(v, off);
    if (tid == 0) sc[2] = v;
  }

  // ---- preload chunk 0 into Tl[0]: 128 threads x 72 floats (18 float4) ----
  float4 P[18];
  {
    const float* p = T + tid * 72;
    #pragma unroll
    for (int q = 0; q < 18; ++q) P[q] = *(const float4*)(p + q*4);
    #pragma unroll
    for (int q = 0; q < 18; ++q) {
      int e = tid*72 + q*4;
      int r = e / 96, c = e - r*96;
      *(float4*)&Tl[0][r*97 + c] = P[q];
    }
  }
  __syncthreads();

  float C = 0.f;
  int cur = 0;
  for (int ch = 0; ch < 48; ++ch) {
    if (ch + 1 < 48) {              // prefetch next chunk into registers
      const float* p = T + (size_t)(ch + 1) * 9216 + tid * 72;
      #pragma unroll
      for (int q = 0; q < 18; ++q) P[q] = *(const float4*)(p + q*4);
    }
    float acc = 0.f;
    if (tid < 96) {                 // matvec: row tid from LDS, z broadcast
      const float* Trow = &Tl[ch & 1][tid * 97];
      float a0 = 0.f, a1 = 0.f;
      #pragma unroll
      for (int q = 0; q < 24; q += 2) {
        float4 t0 = *(const float4*)(Trow + q*4);
        float4 z0 = *(const float4*)&zs[cur][q*4];
        float4 t1 = *(const float4*)(Trow + q*4 + 4);
        float4 z1 = *(const float4*)&zs[cur][q*4 + 4];
        a0 += t0.x*z0.x + t0.y*z0.y + t0.z*z0.z + t0.w*z0.w;
        a1 += t1.x*z1.x + t1.y*z1.y + t1.z*z1.z + t1.w*z1.w;
      }
      acc = a0 + a1;
      if (tid == 95) sc[1] = acc;
    }
    __syncthreads();
    float nv = sc[1];
    float inv = __builtin_amdgcn_rcpf(nv);
    if (tid < 96) zs[cur ^ 1][tid] = acc * inv;
    C += __logf(nv);
    if (ch + 1 < 48) {              // stage prefetched chunk into other buffer
      int b = (ch + 1) & 1;
      #pragma unroll
      for (int q = 0; q < 18; ++q) {
        int e = tid*72 + q*4;
        int r = e / 96, c = e - r*96;
        *(float4*)&Tl[b][r*97 + c] = P[q];
      }
    }
    cur ^= 1;
    __syncthreads();
  }
  if (tid == 0) {
    float lsum = 0.f;
    #pragma unroll
    for (int t = 0; t < 11; ++t) lsum += __logf(zs[cur][84 + t]);
    float logZ = lsum + 11.f * (C + sc[2]);
    out[0] = logZ - sc[0];
  }
}

// ---------------------------------------------------------------------------
extern "C" void kernel_launch(void* const* d_in, const int* in_sizes, int n_in,
                              void* d_out, int out_size, void* d_ws, size_t ws_size,
                              hipStream_t stream)
{
  const float* feats = (const float*)d_in[0];
  const int*   tags  = (const int*)  d_in[1];
  const float* Wd    = (const float*)d_in[2];
  const float* bd    = (const float*)d_in[3];
  const float* Wl    = (const float*)d_in[4];
  const float* bl    = (const float*)d_in[5];
  const float* Wr    = (const float*)d_in[6];
  const float* br    = (const float*)d_in[7];
  const float* Gl    = (const float*)d_in[8];
  const float* bgl   = (const float*)d_in[9];
  const float* Gr    = (const float*)d_in[10];
  const float* bgr   = (const float*)d_in[11];
  const float* Wt    = (const float*)d_in[12];
  const float* bt    = (const float*)d_in[13];
  const float* trans = (const float*)d_in[14];
  float* out = (float*)d_out;

  char* ws = (char*)d_ws;
  unsigned short* featsB = (unsigned short*)(ws + 0);        // 768*512 bf16
  unsigned short* WdB    = (unsigned short*)(ws + 786432);   // 256*512 bf16
  unsigned short* WcB    = (unsigned short*)(ws + 1048576);  // 1024*512 bf16
  float*          bc     = (float*)         (ws + 2097152);  // 1024 f32
  unsigned short* ht     = (unsigned short*)(ws + 2101248);  // 8*768*256 bf16
  float*          Bband  = (float*)         (ws + 5246976);  // 769*96 f32
  float*          Xn     = (float*)         (ws + 5542272);  // 769*96 f32
  float*          muv    = (float*)         (ws + 5837568);  // 769 f32
  float*          T      = (float*)         (ws + 5841664);  // 48*96*96 f32 (1.77 MB)

  prep_kernel<<<4100, 256, 0, stream>>>(feats, Wd, Wl, Wr, Gl, Gr, bl, br, bgl, bgr,
                                        featsB, WdB, WcB, bc);
  hgemm_kernel<<<dim3(12, 4), 256, 0, stream>>>(featsB, WdB, bd, ht);
  for (int sl = 1; sl <= 7; ++sl)
    iter_kernel<<<dim3(12, 16), 256, 0, stream>>>(ht + (size_t)(sl-1)*768*256, WcB, bc,
                                                  ht + (size_t)sl*768*256, 768 - sl);
  band_kernel<<<768, 128, 0, stream>>>(ht, Wt, bt, Bband, Xn, muv);
  chunkT_kernel<<<dim3(5, 48), 256, 0, stream>>>(Xn, muv, trans, T);
  combine_kernel<<<1, 128, 0, stream>>>(T, Bband, muv, trans, bt, tags, out);
}

// Round 8
// 206.437 us; speedup vs baseline: 1.8372x; 1.8372x over previous
//
#include <hip/hip_runtime.h>

typedef __attribute__((ext_vector_type(8))) short short8;
typedef __attribute__((ext_vector_type(4))) float f32x4;

__device__ __forceinline__ float bf2f(short s) {
  return __uint_as_float(((unsigned)(unsigned short)s) << 16);
}
__device__ __forceinline__ unsigned short f2bf(float f) {
  unsigned u = __float_as_uint(f);
  unsigned rounding = 0x7fffu + ((u >> 16) & 1u);
  return (unsigned short)((u + rounding) >> 16);
}

// ---------------- prep: fp32 -> bf16 conversions + combined weight/bias ----
__global__ void prep_kernel(const float* __restrict__ feats, const float* __restrict__ Wd,
                            const float* __restrict__ Wl, const float* __restrict__ Wr,
                            const float* __restrict__ Gl, const float* __restrict__ Gr,
                            const float* __restrict__ bl, const float* __restrict__ br,
                            const float* __restrict__ bgl, const float* __restrict__ bgr,
                            unsigned short* __restrict__ featsB, unsigned short* __restrict__ WdB,
                            unsigned short* __restrict__ WcB, float* __restrict__ bc)
{
  int idx = blockIdx.x * 256 + threadIdx.x;
  if (idx < 393216) {
    featsB[idx] = f2bf(feats[idx]);
  } else if (idx < 524288) {
    int j = idx - 393216;
    WdB[j] = f2bf(Wd[j]);
  } else if (idx < 1048576) {
    int j = idx - 524288;          // Wc[1024][512]: o = j>>9, k = j&511
    int o = j >> 9, k = j & 511;
    float v;
    if (k < 256) v = (o < 256) ? Wl[o*256 + k] : Gl[(o-256)*256 + k];
    else { int k2 = k - 256; v = (o < 256) ? Wr[o*256 + k2] : Gr[(o-256)*256 + k2]; }
    WcB[j] = f2bf(v);
  } else if (idx < 1049600) {
    int o = idx - 1048576;
    bc[o] = (o < 256) ? bl[o] + br[o] : bgl[o-256] + bgr[o-256];
  }
}

// ---------------- h = feats @ Wd.T + bd  (768x512 @ 512x256) ---------------
__global__ __launch_bounds__(256) void hgemm_kernel(const unsigned short* __restrict__ A,
                                                    const unsigned short* __restrict__ W,
                                                    const float* __restrict__ bd,
                                                    unsigned short* __restrict__ C)
{
  __shared__ __align__(16) unsigned short As[64][72];
  __shared__ __align__(16) unsigned short Ws[64][72];
  int p0 = blockIdx.x * 64;
  int n0 = blockIdx.y * 64;
  int tid = threadIdx.x;
  int wave = tid >> 6, lane = tid & 63;
  f32x4 acc[4];
  #pragma unroll
  for (int i = 0; i < 4; ++i)
    #pragma unroll
    for (int j = 0; j < 4; ++j) acc[i][j] = 0.f;

  int lr = tid >> 3;
  int c8 = (tid & 7) * 8;
  for (int kt = 0; kt < 8; ++kt) {
    int kb = kt * 64;
    #pragma unroll
    for (int rr = 0; rr < 64; rr += 32) {
      int row = lr + rr;
      *(short8*)(&As[row][c8]) = *(const short8*)(A + (size_t)(p0 + row)*512 + kb + c8);
      *(short8*)(&Ws[row][c8]) = *(const short8*)(W + (size_t)(n0 + row)*512 + kb + c8);
    }
    __syncthreads();
    int q8 = (lane >> 4) * 8;
    #pragma unroll
    for (int kk = 0; kk < 2; ++kk) {
      short8 b = *(const short8*)(&Ws[wave*16 + (lane & 15)][kk*32 + q8]);
      #pragma unroll
      for (int mt = 0; mt < 4; ++mt) {
        short8 a = *(const short8*)(&As[mt*16 + (lane & 15)][kk*32 + q8]);
        acc[mt] = __builtin_amdgcn_mfma_f32_16x16x32_bf16(a, b, acc[mt], 0, 0, 0);
      }
    }
    __syncthreads();
  }
  int o = n0 + wave*16 + (lane & 15);
  float bias = bd[o];
  #pragma unroll
  for (int mt = 0; mt < 4; ++mt)
    #pragma unroll
    for (int r = 0; r < 4; ++r) {
      int row = p0 + mt*16 + (lane >> 4)*4 + r;
      C[row*256 + o] = f2bf(acc[mt][r] + bias);
    }
}

// ---------------- one span iteration: GEMM + fused gate epilogue -----------
__global__ __launch_bounds__(256) void iter_kernel(const unsigned short* __restrict__ htp,
                                                   const unsigned short* __restrict__ Wc,
                                                   const float* __restrict__ bc,
                                                   unsigned short* __restrict__ htn,
                                                   int Mvalid)
{
  __shared__ __align__(16) unsigned short As[64][72];
  __shared__ __align__(16) unsigned short Ws[64][72];
  __shared__ float Cs[64][64];
  int p0 = blockIdx.x * 64;
  int n0 = blockIdx.y * 16;
  int tid = threadIdx.x;
  int wave = tid >> 6, lane = tid & 63;
  f32x4 acc[4];
  #pragma unroll
  for (int i = 0; i < 4; ++i)
    #pragma unroll
    for (int j = 0; j < 4; ++j) acc[i][j] = 0.f;

  int lr = tid >> 3;
  int c8 = (tid & 7) * 8;
  for (int kt = 0; kt < 8; ++kt) {
    int kb = kt * 64;
    int shift = kb >> 8;
    int kcol = kb & 255;
    #pragma unroll
    for (int rr = 0; rr < 64; rr += 32) {
      int row = lr + rr;
      int grow = p0 + row + shift; if (grow > 767) grow = 767;
      *(short8*)(&As[row][c8]) = *(const short8*)(htp + (size_t)grow*256 + kcol + c8);
      int o = (row >> 4)*256 + n0 + (row & 15);
      *(short8*)(&Ws[row][c8]) = *(const short8*)(Wc + (size_t)o*512 + kb + c8);
    }
    __syncthreads();
    int q8 = (lane >> 4) * 8;
    #pragma unroll
    for (int kk = 0; kk < 2; ++kk) {
      short8 b = *(const short8*)(&Ws[wave*16 + (lane & 15)][kk*32 + q8]);
      #pragma unroll
      for (int mt = 0; mt < 4; ++mt) {
        short8 a = *(const short8*)(&As[mt*16 + (lane & 15)][kk*32 + q8]);
        acc[mt] = __builtin_amdgcn_mfma_f32_16x16x32_bf16(a, b, acc[mt], 0, 0, 0);
      }
    }
    __syncthreads();
  }
  #pragma unroll
  for (int mt = 0; mt < 4; ++mt)
    #pragma unroll
    for (int r = 0; r < 4; ++r)
      Cs[mt*16 + (lane >> 4)*4 + r][wave*16 + (lane & 15)] = acc[mt][r];
  __syncthreads();

  int dl = tid & 15;
  int d = n0 + dl;
  float bz = bc[d], b0 = bc[256 + d], b1 = bc[512 + d], b2v = bc[768 + d];
  for (int pr = tid >> 4; pr < 64; pr += 16) {
    int p = p0 + pr;
    if (p >= Mvalid) continue;
    float z  = Cs[pr][dl]      + bz;
    float g0 = Cs[pr][16 + dl] + b0;
    float g1 = Cs[pr][32 + dl] + b1;
    float g2 = Cs[pr][48 + dl] + b2v;
    float l = bf2f((short)htp[p*256 + d]);
    float r = bf2f((short)htp[(p+1)*256 + d]);
    float hh = 4.f / (1.f + __expf(-z)) - 2.f;
    float mg = fmaxf(g0, fmaxf(g1, g2));
    float e0 = __expf(g0 - mg), e1 = __expf(g1 - mg), e2 = __expf(g2 - mg);
    float inv = 1.f / (e0 + e1 + e2);
    htn[p*256 + d] = f2bf((e0*hh + e1*l + e2*r) * inv);
  }
}

// ---------------- band: log scores, row max, normalized exp ----------------
__global__ __launch_bounds__(128) void band_kernel(const unsigned short* __restrict__ htall,
                                                   const float* __restrict__ Wt,
                                                   const float* __restrict__ bt,
                                                   float* __restrict__ Bband,   // [769][96] log
                                                   float* __restrict__ Xn,      // [769][96] exp(B-mu)
                                                   float* __restrict__ mu)      // [769]
{
  __shared__ __align__(16) unsigned short rows[8][264];
  __shared__ float sred[96];
  __shared__ float smu;
  int i = blockIdx.x + 1;     // 1..768
  int tid = threadIdx.x;
  for (int q = tid; q < 256; q += 128) {
    int k = q >> 5, cc = (q & 31) * 8;
    int p = i - 8 + k, sl = 7 - k;
    short8 v;
    if (p >= 0) {
      v = *(const short8*)(htall + ((size_t)sl*768 + p)*256 + cc);
    } else {
      for (int j = 0; j < 8; ++j) v[j] = 0;
    }
    *(short8*)(&rows[k][cc]) = v;
  }
  __syncthreads();
  float res = -1e30f;
  if (tid < 96) {
    int t = tid >> 3, k = tid & 7;
    int p = i - 8 + k;
    if (p >= 0) {
      float acc = 0.f;
      for (int dch = 0; dch < 256; dch += 8) {
        float4 wa = *(const float4*)(Wt + t*256 + dch);
        float4 wb = *(const float4*)(Wt + t*256 + dch + 4);
        short8 hv = *(const short8*)(&rows[k][dch]);
        acc += wa.x*bf2f(hv[0]) + wa.y*bf2f(hv[1]) + wa.z*bf2f(hv[2]) + wa.w*bf2f(hv[3])
             + wb.x*bf2f(hv[4]) + wb.y*bf2f(hv[5]) + wb.z*bf2f(hv[6]) + wb.w*bf2f(hv[7]);
      }
      res = acc + bt[t];
    }
    Bband[(size_t)i*96 + tid] = res;
    sred[tid] = res;
  }
  __syncthreads();
  if (tid < 32) {
    float m = fmaxf(sred[tid], fmaxf(sred[tid+32], sred[tid+64]));
    #pragma unroll
    for (int off = 16; off; off >>= 1) m = fmaxf(m, __shfl_down(m, off));
    if (tid == 0) { mu[i] = m; smu = m; }
  }
  __syncthreads();
  if (tid < 96) Xn[(size_t)i*96 + tid] = __expf(res - smu);  // masked -> 0
}

// ---------------- chunk transfer matrices (parallel scan, phase 1) ---------
__global__ __launch_bounds__(256) void chunkT_kernel(const float* __restrict__ Xn,
                                                     const float* __restrict__ mu,
                                                     const float* __restrict__ trans,
                                                     float* __restrict__ T,
                                                     float* __restrict__ C0)
{
  int chunk = blockIdx.y;
  int a = chunk * 16;               // steps a+1 .. a+16
  int tid = threadIdx.x;
  if (blockIdx.x == 0 && tid == 0) C0[chunk] = 0.f;
  int wv = tid >> 6;
  int lane = tid & 63;
  int g = lane / 12;                // 12-lane group within wave (g=5: shadow)
  int t = lane - g * 12;            // tag owned by this lane
  int cidx = blockIdx.x * 20 + wv * 5 + g;
  bool active = (g < 5) && (cidx < 96);
  int c = active ? cidx : 95;
  int s = c / 12, tau = c - s * 12; // basis: na_{a-7+s} = e_tau
  float Etc[12];
  #pragma unroll
  for (int j = 0; j < 12; ++j) Etc[j] = __expf(trans[j*12 + t]);  // E[j][t]
  float NA[8], V[8];
  #pragma unroll
  for (int j = 0; j < 8; ++j) { NA[j] = 0.f; V[j] = 0.f; }
  #pragma unroll
  for (int j = 0; j < 8; ++j) if (j == s) {
    NA[j] = (t == tau) ? 1.f : 0.f;
    V[j]  = Etc[tau];               // v = E^T e_tau -> E[tau][t]
  }
  int gb = (g * 12) * 4;            // bpermute byte base of this group
  #pragma unroll
  for (int m = 1; m <= 16; ++m) {
    const float* xr = Xn + (size_t)(a + m) * 96 + t * 8;
    float4 x0 = *(const float4*)xr;
    float4 x1 = *(const float4*)(xr + 4);
    float sf = __expf(-mu[a + m]);  // uniform state scale for this step
    float na = x0.x*V[0] + x0.y*V[1] + x0.z*V[2] + x0.w*V[3]
             + x1.x*V[4] + x1.y*V[5] + x1.z*V[6] + x1.w*V[7];
    int nai = __float_as_int(na);
    float nb[12];
    #pragma unroll
    for (int j = 0; j < 12; ++j)
      nb[j] = __int_as_float(__builtin_amdgcn_ds_bpermute(gb + j*4, nai));
    float p0 = nb[0]*Etc[0] + nb[1]*Etc[1] + nb[2]*Etc[2]  + nb[3]*Etc[3];
    float p1 = nb[4]*Etc[4] + nb[5]*Etc[5] + nb[6]*Etc[6]  + nb[7]*Etc[7];
    float p2 = nb[8]*Etc[8] + nb[9]*Etc[9] + nb[10]*Etc[10] + nb[11]*Etc[11];
    float v = (p0 + p1) + p2;
    #pragma unroll
    for (int k = 0; k < 7; ++k) { NA[k] = NA[k+1]*sf; V[k] = V[k+1]*sf; }
    NA[7] = na; V[7] = v;           // na already carries e^{-mu} via Xn
  }
  if (active) {
    float* dst = T + (size_t)chunk * 9216 + c;
    #pragma unroll
    for (int j = 0; j < 8; ++j) dst[(size_t)(j*12 + t) * 96] = NA[j];
  }
}

// ---------------- tree level: Tout[j] = norm(Tin[2j+1]) * norm(Tin[2j]) ----
// grid: dim3(2, nOut). blockIdx.x selects 48-column slice of the output.
// Inputs max-normalized at staging (consistent across both slice-blocks);
// log scales accumulated in Cout. Entries all >= 0; product entries <= 96.
#define TPAD 100
__global__ __launch_bounds__(256) void treemul_kernel(const float* __restrict__ Tin,
                                                      const float* __restrict__ Cin,
                                                      float* __restrict__ Tout,
                                                      float* __restrict__ Cout)
{
  __shared__ float Bs[96 * TPAD];   // B row-major padded
  __shared__ float Acs[96 * TPAD];  // A col-major padded
  __shared__ float red[8];
  int j = blockIdx.y;
  int cs = blockIdx.x * 48;
  const float* Ag = Tin + (size_t)(2*j) * 9216;      // applied first
  const float* Bg = Tin + (size_t)(2*j + 1) * 9216;  // applied second
  int tid = threadIdx.x;
  int wv = tid >> 6, lane = tid & 63;

  float4 av[9], bv[9];
  const float* ap = Ag + tid * 36;
  const float* bp = Bg + tid * 36;
  #pragma unroll
  for (int q = 0; q < 9; ++q) av[q] = *(const float4*)(ap + q*4);
  #pragma unroll
  for (int q = 0; q < 9; ++q) bv[q] = *(const float4*)(bp + q*4);
  float ma = 0.f, mb = 0.f;
  #pragma unroll
  for (int q = 0; q < 9; ++q) {
    ma = fmaxf(ma, fmaxf(fmaxf(av[q].x, av[q].y), fmaxf(av[q].z, av[q].w)));
    mb = fmaxf(mb, fmaxf(fmaxf(bv[q].x, bv[q].y), fmaxf(bv[q].z, bv[q].w)));
  }
  #pragma unroll
  for (int off = 32; off; off >>= 1) {
    ma = fmaxf(ma, __shfl_down(ma, off));
    mb = fmaxf(mb, __shfl_down(mb, off));
  }
  if (lane == 0) { red[wv] = ma; red[4 + wv] = mb; }
  __syncthreads();
  float fa = fmaxf(fmaxf(red[0], red[1]), fmaxf(red[2], red[3]));
  float fb = fmaxf(fmaxf(red[4], red[5]), fmaxf(red[6], red[7]));
  float ia = 1.0f / fa, ib = 1.0f / fb;

  #pragma unroll
  for (int q = 0; q < 9; ++q) {          // stage scaled: B row-major
    int e = tid*36 + q*4;
    int r = e / 96, k = e - r*96;
    float4 b = bv[q];
    b.x *= ib; b.y *= ib; b.z *= ib; b.w *= ib;
    *(float4*)&Bs[r*TPAD + k] = b;
    float4 a = av[q];                    // A col-major (scatter)
    Acs[(k+0)*TPAD + r] = a.x * ia;      // note: here e's row r is A's row,
    Acs[(k+1)*TPAD + r] = a.y * ia;      // e%96 = k is A's col -> Acs[col][row]
    Acs[(k+2)*TPAD + r] = a.z * ia;
    Acs[(k+3)*TPAD + r] = a.w * ia;
  }
  __syncthreads();

  int tr = tid >> 4, tc = tid & 15;
  int r0 = tr * 6, c0 = cs + tc * 3;
  float acc[6][3];
  #pragma unroll
  for (int i = 0; i < 6; ++i)
    #pragma unroll
    for (int m = 0; m < 3; ++m) acc[i][m] = 0.f;
  for (int k = 0; k < 96; k += 4) {
    float4 a0 = *(const float4*)&Acs[(c0+0)*TPAD + k];
    float4 a1 = *(const float4*)&Acs[(c0+1)*TPAD + k];
    float4 a2 = *(const float4*)&Acs[(c0+2)*TPAD + k];
    #pragma unroll
    for (int i = 0; i < 6; ++i) {
      float4 b = *(const float4*)&Bs[(r0+i)*TPAD + k];
      acc[i][0] += b.x*a0.x + b.y*a0.y + b.z*a0.z + b.w*a0.w;
      acc[i][1] += b.x*a1.x + b.y*a1.y + b.z*a1.z + b.w*a1.w;
      acc[i][2] += b.x*a2.x + b.y*a2.y + b.z*a2.z + b.w*a2.w;
    }
  }
  float* op = Tout + (size_t)j * 9216;
  #pragma unroll
  for (int i = 0; i < 6; ++i)
    #pragma unroll
    for (int m = 0; m < 3; ++m)
      op[(size_t)(r0+i)*96 + c0 + m] = acc[i][m];
  if (blockIdx.x == 0 && tid == 0)
    Cout[j] = Cin[2*j] + Cin[2*j + 1] + __logf(fa) + __logf(fb);
}

// ---------------- final: 3 matvecs + gold + musum --------------------------
__global__ __launch_bounds__(256, 1) void final_kernel(const float* __restrict__ Tm,
    const float* __restrict__ Cm, const float* __restrict__ Bband,
    const float* __restrict__ mu, const float* __restrict__ trans,
    const float* __restrict__ bt, const int* __restrict__ tags,
    float* __restrict__ out)
{
  __shared__ float Qs[2][96 * TPAD];
  __shared__ float vv[4][96];
  __shared__ float red[8];     // gold partials [0..3], mu partials [4..7]
  __shared__ float redm[4];    // matvec max partials
  int tid = threadIdx.x;
  int wv = tid >> 6, lane = tid & 63;

  // stage Q0 (prefetch into regs)
  float4 P[9];
  const float* p0 = Tm + tid * 36;
  #pragma unroll
  for (int q = 0; q < 9; ++q) P[q] = *(const float4*)(p0 + q*4);

  // gold (one span per thread, 96 spans) + musum
  float gold = 0.f;
  if (tid < 96) {
    int a = tags[tid*4+0], b = tags[tid*4+1], cc = tags[tid*4+2], d = tags[tid*4+3];
    float v = trans[cc*12 + d];
    int sl = b - a;
    if (sl >= 0 && sl < 8) v += Bband[(size_t)(b+1)*96 + d*8 + (7 - sl)];
    else v += bt[d];
    gold = v;
  }
  float mp = 0.f;
  for (int q = tid; q < 768; q += 256) mp += mu[1 + q];
  #pragma unroll
  for (int off = 32; off; off >>= 1) {
    gold += __shfl_down(gold, off);
    mp   += __shfl_down(mp, off);
  }
  if (lane == 0) { red[wv] = gold; red[4 + wv] = mp; }

  #pragma unroll
  for (int q = 0; q < 9; ++q) {
    int e = tid*36 + q*4;
    int r = e / 96, k = e - r*96;
    *(float4*)&Qs[0][r*TPAD + k] = P[q];
  }
  if (tid < 96) vv[0][tid] = (tid == 94) ? 1.f : 0.f;  // onehot(START=84+10)
  __syncthreads();
  float gold_t = red[0] + red[1] + red[2] + red[3];
  float musum  = red[4] + red[5] + red[6] + red[7];
  float Ct = Cm[0] + Cm[1] + Cm[2];

  #pragma unroll
  for (int s = 0; s < 3; ++s) {
    if (s < 2) {                       // prefetch next matrix during matvec
      const float* pn = Tm + (size_t)(s+1)*9216 + tid*36;
      #pragma unroll
      for (int q = 0; q < 9; ++q) P[q] = *(const float4*)(pn + q*4);
    }
    float acc = 0.f;
    if (tid < 96) {
      const float* Qr = &Qs[s & 1][tid * TPAD];
      #pragma unroll
      for (int k = 0; k < 96; k += 4) {
        float4 qv = *(const float4*)(Qr + k);
        float4 zv = *(const float4*)&vv[s][k];
        acc += qv.x*zv.x + qv.y*zv.y + qv.z*zv.z + qv.w*zv.w;
      }
    }
    float am = (tid < 96) ? acc : 0.f;
    #pragma unroll
    for (int off = 32; off; off >>= 1) am = fmaxf(am, __shfl_down(am, off));
    if (lane == 0) redm[wv] = am;
    __syncthreads();
    float mx = fmaxf(fmaxf(redm[0], redm[1]), fmaxf(redm[2], redm[3]));
    Ct += __logf(mx);
    if (tid < 96) vv[s+1][tid] = acc / mx;
    if (s < 2) {
      #pragma unroll
      for (int q = 0; q < 9; ++q) {
        int e = tid*36 + q*4;
        int r = e / 96, k = e - r*96;
        *(float4*)&Qs[(s+1)&1][r*TPAD + k] = P[q];
      }
    }
    __syncthreads();
  }
  if (tid == 0) {
    float lsum = 0.f;
    #pragma unroll
    for (int t = 0; t < 11; ++t) lsum += __logf(vv[3][84 + t]);
    out[0] = lsum + 11.f * (Ct + musum) - gold_t;
  }
}

// ---------------------------------------------------------------------------
extern "C" void kernel_launch(void* const* d_in, const int* in_sizes, int n_in,
                              void* d_out, int out_size, void* d_ws, size_t ws_size,
                              hipStream_t stream)
{
  const float* feats = (const float*)d_in[0];
  const int*   tags  = (const int*)  d_in[1];
  const float* Wd    = (const float*)d_in[2];
  const float* bd    = (const float*)d_in[3];
  const float* Wl    = (const float*)d_in[4];
  const float* bl    = (const float*)d_in[5];
  const float* Wr    = (const float*)d_in[6];
  const float* br    = (const float*)d_in[7];
  const float* Gl    = (const float*)d_in[8];
  const float* bgl   = (const float*)d_in[9];
  const float* Gr    = (const float*)d_in[10];
  const float* bgr   = (const float*)d_in[11];
  const float* Wt    = (const float*)d_in[12];
  const float* bt    = (const float*)d_in[13];
  const float* trans = (const float*)d_in[14];
  float* out = (float*)d_out;

  char* ws = (char*)d_ws;
  unsigned short* featsB = (unsigned short*)(ws + 0);        // 768*512 bf16 (dead after hgemm)
  unsigned short* WdB    = (unsigned short*)(ws + 786432);   // 256*512 bf16 (dead after hgemm)
  unsigned short* WcB    = (unsigned short*)(ws + 1048576);  // 1024*512 bf16 (dead after iters)
  float*          bc     = (float*)         (ws + 2097152);  // 1024 f32
  unsigned short* ht     = (unsigned short*)(ws + 2101248);  // 8*768*256 bf16 (dead after band)
  float*          Bband  = (float*)         (ws + 5246976);  // 769*96 f32
  float*          Xn     = (float*)         (ws + 5542272);  // 769*96 f32
  float*          muv    = (float*)         (ws + 5837568);  // 769 f32
  float*          T      = (float*)         (ws + 5841664);  // 48*9216 f32 (1.73 MB)
  float*          Tb     = (float*)         (ws + 0);        // 24*9216 f32 (overlays featsB+WdB)
  float*          C0     = (float*)         (ws + 1048576);  // 48 f32 (overlays WcB)
  float*          Ca     = (float*)         (ws + 1048832);  // 24 f32
  float*          Cb     = (float*)         (ws + 1049088);  // 24 f32

  prep_kernel<<<4100, 256, 0, stream>>>(feats, Wd, Wl, Wr, Gl, Gr, bl, br, bgl, bgr,
                                        featsB, WdB, WcB, bc);
  hgemm_kernel<<<dim3(12, 4), 256, 0, stream>>>(featsB, WdB, bd, ht);
  for (int sl = 1; sl <= 7; ++sl)
    iter_kernel<<<dim3(12, 16), 256, 0, stream>>>(ht + (size_t)(sl-1)*768*256, WcB, bc,
                                                  ht + (size_t)sl*768*256, 768 - sl);
  band_kernel<<<768, 128, 0, stream>>>(ht, Wt, bt, Bband, Xn, muv);
  chunkT_kernel<<<dim3(5, 48), 256, 0, stream>>>(Xn, muv, trans, T, C0);
  treemul_kernel<<<dim3(2, 24), 256, 0, stream>>>(T,  C0, Tb, Ca);   // 48 -> 24
  treemul_kernel<<<dim3(2, 12), 256, 0, stream>>>(Tb, Ca, T,  Cb);   // 24 -> 12
  treemul_kernel<<<dim3(2,  6), 256, 0, stream>>>(T,  Cb, Tb, Ca);   // 12 -> 6
  treemul_kernel<<<dim3(2,  3), 256, 0, stream>>>(Tb, Ca, T,  Cb);   //  6 -> 3
  final_kernel<<<1, 256, 0, stream>>>(T, Cb, Bband, muv, trans, bt, tags, out);
}